// Round 4
// baseline (531.298 us; speedup 1.0000x reference)
//
#include <hip/hip_runtime.h>

#define D 128
#define NG 128
#define EPB 8192      // edges per phase-A block
#define NB1MAX 512    // max coarse buckets (N/256); N=100k -> 391

typedef unsigned short ushort_t;
typedef __bf16 bf16x8 __attribute__((ext_vector_type(8)));
typedef float floatx4 __attribute__((ext_vector_type(4)));

static __device__ __forceinline__ unsigned short f2bf(float f) {
    unsigned u = __float_as_uint(f);
    unsigned r = (u + 0x7fffu + ((u >> 16) & 1u)) >> 16;  // RNE
    return (unsigned short)r;
}

// ---------- Phase A1: per-(block, bucket) histogram, LDS-aggregated ----------
__global__ __launch_bounds__(256) void k_ahist(const int* __restrict__ dst, int E, int nb1,
                                               int* __restrict__ cnt1) {
    __shared__ int hist[NB1MAX];
    int tid = threadIdx.x;
    for (int b = tid; b < nb1; b += 256) hist[b] = 0;
    __syncthreads();
    int base = blockIdx.x * EPB;
    for (int k = tid; k < EPB; k += 256) {
        int i = base + k;
        if (i < E) atomicAdd(&hist[dst[i] >> 8], 1);
    }
    __syncthreads();
    for (int b = tid; b < nb1; b += 256) cnt1[blockIdx.x * nb1 + b] = hist[b];  // [blk][b], coalesced
}

// ---------- k_mid (single block): pool/done zero, packW, graph counts, offset scan ----------
// cnt1[blk][b] (counts) -> in-place cnt1[blk][b] = global base offset for that (block,bucket) run.
__global__ __launch_bounds__(1024) void k_mid(const float* __restrict__ W, ushort_t* __restrict__ Wp,
                                              const int* __restrict__ batch, int N,
                                              int* __restrict__ cnt, int* __restrict__ cnt1,
                                              int nb1, int nblk,
                                              float* __restrict__ pool, int* __restrict__ done) {
    __shared__ int tot[512];
    int tid = threadIdx.x;

    // zero pool + done counter
    for (int i = tid; i < NG * D; i += 1024) pool[i] = 0.f;
    if (tid == 0) *done = 0;

    // pack W: fp32 [k][c] -> bf16 col-major Wp[c][k]
    for (int t = tid; t < D * D; t += 1024) {
        int c = t >> 7, k = t & 127;
        Wp[t] = f2bf(W[k * D + c]);
    }

    // per-graph node counts (batch sorted)
    if (tid < NG) {
        int g = tid;
        int lo = 0, hi = N;
        while (lo < hi) { int mid = (lo + hi) >> 1; if (batch[mid] < g) lo = mid + 1; else hi = mid; }
        int a = lo;
        hi = N;
        while (lo < hi) { int mid = (lo + hi) >> 1; if (batch[mid] < g + 1) lo = mid + 1; else hi = mid; }
        cnt[g] = lo - a;
    }

    // pass 1: per-bucket running prefix over blocks (in-place exclusive), totals to LDS
    int run = 0;
    if (tid < nb1) {
        for (int blk = 0; blk < nblk; ++blk) {
            int idx = blk * nb1 + tid;
            int v = cnt1[idx];
            cnt1[idx] = run;
            run += v;
        }
    }
    if (tid < 512) tot[tid] = (tid < nb1) ? run : 0;
    __syncthreads();

    // exclusive scan of bucket totals (Hillis-Steele over 512)
    int v0 = (tid < 512) ? tot[tid] : 0;
    for (int off = 1; off < 512; off <<= 1) {
        int tv = (tid < 512 && tid >= off) ? tot[tid - off] : 0;
        __syncthreads();
        if (tid < 512) tot[tid] += tv;
        __syncthreads();
    }
    int segbase = (tid < 512) ? tot[tid] - v0 : 0;

    // pass 2: add segment base
    if (tid < nb1) {
        for (int blk = 0; blk < nblk; ++blk) cnt1[blk * nb1 + tid] += segbase;
    }
}

// ---------- Phase A2: scatter packed (src | fine-dst<<24) into bucket segments ----------
__global__ __launch_bounds__(256) void k_ascatter(const int* __restrict__ src, const int* __restrict__ dst, int E,
                                                  int nb1, const int* __restrict__ off1,
                                                  int* __restrict__ ebuf) {
    __shared__ int curs[NB1MAX];
    int tid = threadIdx.x;
    for (int b = tid; b < nb1; b += 256) curs[b] = off1[blockIdx.x * nb1 + b];
    __syncthreads();
    int base = blockIdx.x * EPB;
    for (int k = tid; k < EPB; k += 256) {
        int i = base + k;
        if (i < E) {
            int d = dst[i];
            int pos = atomicAdd(&curs[d >> 8], 1);
            ebuf[pos] = src[i] | ((d & 255) << 24);
        }
    }
}

// ---------- Phase B: per-bucket fine sort -> rs, deg, csr (LDS atomics only) ----------
__global__ __launch_bounds__(256) void k_bucket(const int* __restrict__ ebuf, const int* __restrict__ off1,
                                                int E, int nb1, int N,
                                                int* __restrict__ rs, int* __restrict__ deg,
                                                int* __restrict__ csr) {
    __shared__ int hist[256];
    __shared__ int sc[256];
    __shared__ int curs[256];
    int tid = threadIdx.x;
    int b = blockIdx.x;
    int s = off1[b];                               // block-0 offset == segment base
    int e = (b + 1 < nb1) ? off1[b + 1] : E;
    int n0 = b << 8;

    hist[tid] = 0;
    __syncthreads();
    for (int i = s + tid; i < e; i += 256) atomicAdd(&hist[(unsigned)ebuf[i] >> 24], 1);
    __syncthreads();
    int v = hist[tid];
    sc[tid] = v;
    __syncthreads();
    for (int off = 1; off < 256; off <<= 1) {
        int t = (tid >= off) ? sc[tid - off] : 0;
        __syncthreads();
        sc[tid] += t;
        __syncthreads();
    }
    int excl = sc[tid] - v;
    int node = n0 + tid;
    if (node < N) {
        rs[node] = s + excl;
        deg[node] = v;
    }
    curs[tid] = s + excl;
    __syncthreads();
    for (int i = s + tid; i < e; i += 256) {
        int p = ebuf[i];
        int pos = atomicAdd(&curs[(unsigned)p >> 24], 1);
        csr[pos] = p & 0x00FFFFFF;
    }
}

// ---------- MFMA GEMM: h[r][c] = bf16( dinv[r] * sum_k x[r][k]*W[k][c] ) ----------
__global__ __launch_bounds__(256) void k_gemm(const float* __restrict__ x, const ushort_t* __restrict__ Wp,
                                              const int* __restrict__ deg, ushort_t* __restrict__ h, int N) {
    __shared__ ushort_t hs[64][130];
    const int tid = threadIdx.x;
    const int w = tid >> 6;
    const int lane = tid & 63;
    const int q = lane >> 4;
    const int m = lane & 15;
    const int row0 = blockIdx.x * 64;
    const int arow = row0 + w * 16 + m;

    floatx4 acc[8];
#pragma unroll
    for (int nt = 0; nt < 8; ++nt) acc[nt] = (floatx4){0.f, 0.f, 0.f, 0.f};

    const bool rowok = (arow < N);
    const float* xrow = x + (size_t)arow * D;

#pragma unroll
    for (int kb = 0; kb < 4; ++kb) {
        union { bf16x8 v; ushort_t u[8]; } af;
        if (rowok) {
            float4 v0 = *(const float4*)&xrow[kb * 32 + q * 8];
            float4 v1 = *(const float4*)&xrow[kb * 32 + q * 8 + 4];
            af.u[0] = f2bf(v0.x); af.u[1] = f2bf(v0.y); af.u[2] = f2bf(v0.z); af.u[3] = f2bf(v0.w);
            af.u[4] = f2bf(v1.x); af.u[5] = f2bf(v1.y); af.u[6] = f2bf(v1.z); af.u[7] = f2bf(v1.w);
        } else {
#pragma unroll
            for (int j = 0; j < 8; ++j) af.u[j] = 0;
        }
#pragma unroll
        for (int nt = 0; nt < 8; ++nt) {
            int c = nt * 16 + m;
            const bf16x8 bf = *(const bf16x8*)(Wp + (size_t)c * D + kb * 32 + q * 8);
            acc[nt] = __builtin_amdgcn_mfma_f32_16x16x32_bf16(af.v, bf, acc[nt], 0, 0, 0);
        }
    }

    float di[4];
#pragma unroll
    for (int r = 0; r < 4; ++r) {
        int row = row0 + w * 16 + q * 4 + r;
        di[r] = (row < N) ? rsqrtf((float)(deg[row] + 1)) : 0.f;
    }
#pragma unroll
    for (int nt = 0; nt < 8; ++nt) {
        int c = nt * 16 + m;
#pragma unroll
        for (int r = 0; r < 4; ++r) {
            hs[w * 16 + q * 4 + r][c] = f2bf(acc[nt][r] * di[r]);
        }
    }
    __syncthreads();
#pragma unroll
    for (int it = 0; it < 8; ++it) {
        int f = it * 256 + tid;
        int r = f >> 5;
        int cq = f & 31;
        int row = row0 + r;
        if (row < N) {
            const ushort_t* p = &hs[r][cq * 4];
            uint2 vv;
            vv.x = (unsigned)p[0] | ((unsigned)p[1] << 16);
            vv.y = (unsigned)p[2] | ((unsigned)p[3] << 16);
            *(uint2*)&h[(size_t)row * D + cq * 4] = vv;
        }
    }
}

// ---------- gather + finalize + register pooling + last-block pool division ----------
__global__ __launch_bounds__(256) void k_gather(const ushort_t* __restrict__ h, const int* __restrict__ rs,
                                                const int* __restrict__ deg, const int* __restrict__ csr,
                                                const int* __restrict__ batch, const float* __restrict__ b,
                                                const float* __restrict__ pa, const int* __restrict__ cnt,
                                                float* __restrict__ pool, float* __restrict__ out,
                                                int* __restrict__ done, int N, int npw) {
    __shared__ int ticket;
    int wid = blockIdx.x * 4 + (threadIdx.x >> 6);
    int lane = threadIdx.x & 63;
    int n0 = wid * npw;
    int n1 = n0 + npw;
    if (n1 > N) n1 = N;

    float2 bb = *(const float2*)&b[lane * 2];
    float2 aa = *(const float2*)&pa[lane * 2];
    float px = 0.f, py = 0.f;
    int curg = -1;

    for (int node = n0; node < n1; ++node) {
        int g = batch[node];
        if (g != curg) {
            if (curg >= 0) {
                atomicAdd(&pool[(size_t)curg * D + lane * 2], px);
                atomicAdd(&pool[(size_t)curg * D + lane * 2 + 1], py);
            }
            px = 0.f; py = 0.f; curg = g;
        }
        unsigned sv = *(const unsigned*)&h[(size_t)node * D + lane * 2];
        float accx = __uint_as_float(sv << 16);
        float accy = __uint_as_float(sv & 0xffff0000u);

        int start = rs[node];
        int len = deg[node];
        for (int o = 0; o < len; o += 64) {
            int m = len - o;
            if (m > 64) m = 64;
            int idx = (o + lane < len) ? csr[start + o + lane] : 0;
            int j = 0;
            for (; j + 4 <= m; j += 4) {
                int s0 = __shfl(idx, j);
                int s1 = __shfl(idx, j + 1);
                int s2 = __shfl(idx, j + 2);
                int s3 = __shfl(idx, j + 3);
                unsigned v0 = *(const unsigned*)&h[(size_t)s0 * D + lane * 2];
                unsigned v1 = *(const unsigned*)&h[(size_t)s1 * D + lane * 2];
                unsigned v2 = *(const unsigned*)&h[(size_t)s2 * D + lane * 2];
                unsigned v3 = *(const unsigned*)&h[(size_t)s3 * D + lane * 2];
                accx += __uint_as_float(v0 << 16);  accy += __uint_as_float(v0 & 0xffff0000u);
                accx += __uint_as_float(v1 << 16);  accy += __uint_as_float(v1 & 0xffff0000u);
                accx += __uint_as_float(v2 << 16);  accy += __uint_as_float(v2 & 0xffff0000u);
                accx += __uint_as_float(v3 << 16);  accy += __uint_as_float(v3 & 0xffff0000u);
            }
            for (; j < m; ++j) {
                int s0 = __shfl(idx, j);
                unsigned v0 = *(const unsigned*)&h[(size_t)s0 * D + lane * 2];
                accx += __uint_as_float(v0 << 16);  accy += __uint_as_float(v0 & 0xffff0000u);
            }
        }
        float dinv = rsqrtf((float)(len + 1));
        float vx = accx * dinv + bb.x;
        float vy = accy * dinv + bb.y;
        vx = vx > 0.f ? vx : aa.x * vx;
        vy = vy > 0.f ? vy : aa.y * vy;
        float ss = vx * vx + vy * vy;
#pragma unroll
        for (int o = 32; o > 0; o >>= 1) ss += __shfl_xor(ss, o);
        float inv = 1.0f / fmaxf(sqrtf(ss), 1e-12f);
        px += vx * inv;
        py += vy * inv;
    }
    if (curg >= 0) {
        atomicAdd(&pool[(size_t)curg * D + lane * 2], px);
        atomicAdd(&pool[(size_t)curg * D + lane * 2 + 1], py);
    }

    // completion: last block divides pool by counts and writes out
    __threadfence();
    __syncthreads();
    if (threadIdx.x == 0) ticket = atomicAdd(done, 1);
    __syncthreads();
    if (ticket == (int)gridDim.x - 1) {
        for (int i = threadIdx.x; i < NG * D; i += 256) {
            float s = __hip_atomic_load(&pool[i], __ATOMIC_RELAXED, __HIP_MEMORY_SCOPE_AGENT);
            out[i] = s / fmaxf((float)cnt[i >> 7], 1.0f);
        }
    }
}

extern "C" void kernel_launch(void* const* d_in, const int* in_sizes, int n_in,
                              void* d_out, int out_size, void* d_ws, size_t ws_size,
                              hipStream_t stream) {
    const float* x = (const float*)d_in[0];
    const int* ei = (const int*)d_in[1];
    const int* batch = (const int*)d_in[2];
    const float* W = (const float*)d_in[3];
    const float* b = (const float*)d_in[4];
    const float* pa = (const float*)d_in[5];
    float* out = (float*)d_out;

    const int N = in_sizes[0] / D;
    const int E = in_sizes[1] / 2;
    const int* src = ei;
    const int* dst = ei + E;

    const int nb1 = (N + 255) >> 8;           // coarse buckets
    const int nblk = (E + EPB - 1) / EPB;     // phase-A blocks
    const int M = nb1 * nblk;

    char* w = (char*)d_ws;
    auto carve = [&](size_t bytes) {
        void* p = (void*)w;
        w += (bytes + 255) & ~(size_t)255;
        return p;
    };
    ushort_t* h = (ushort_t*)carve((size_t)N * D * sizeof(ushort_t));   // 25.6 MB
    ushort_t* Wp = (ushort_t*)carve((size_t)D * D * sizeof(ushort_t));
    int* deg = (int*)carve((size_t)N * sizeof(int));
    int* rs = (int*)carve((size_t)N * sizeof(int));
    int* csr = (int*)carve((size_t)E * sizeof(int));                    // 6.4 MB
    int* cnt1 = (int*)carve((size_t)M * sizeof(int));
    int* ebuf = (int*)carve((size_t)E * sizeof(int));                   // 6.4 MB
    int* cnt = (int*)carve(NG * sizeof(int));
    float* pool = (float*)carve((size_t)NG * D * sizeof(float));
    int* done = (int*)carve(256);

    const int GB = 2048;                       // gather blocks (4 waves each)
    const int npw = (N + GB * 4 - 1) / (GB * 4);

    k_ahist<<<nblk, 256, 0, stream>>>(dst, E, nb1, cnt1);
    k_mid<<<1, 1024, 0, stream>>>(W, Wp, batch, N, cnt, cnt1, nb1, nblk, pool, done);
    k_ascatter<<<nblk, 256, 0, stream>>>(src, dst, E, nb1, cnt1, ebuf);
    k_bucket<<<nb1, 256, 0, stream>>>(ebuf, cnt1, E, nb1, N, rs, deg, csr);
    k_gemm<<<(N + 63) / 64, 256, 0, stream>>>(x, Wp, deg, h, N);
    k_gather<<<GB, 256, 0, stream>>>(h, rs, deg, csr, batch, b, pa, cnt, pool, out, done, N, npw);
}